// Round 4
// baseline (80.887 us; speedup 1.0000x reference)
//
#include <hip/hip_runtime.h>
#include <math.h>

#define NB 384          // batch size B
#define ND4 64          // D/4 = 256/4
#define NT 256          // threads per block (4 waves)
#define NWV 4           // waves per block
#define TMARGIN 0.3f

// One block per anchor (384 blocks x 256 threads, 4 waves).
// Phase 1: dist row, 8 lanes per row (32 rows in flight), unroll-4 for MLP.
// Phase 2: negmin + positives list. Phase 3: semi-hard mining, 1 positive/wave.
// Finalize: atomic partials + ticket; last block writes the mean loss.
__global__ __launch_bounds__(NT) void triplet_main(
    const float4* __restrict__ E4, const int* __restrict__ labels,
    float* __restrict__ gsum, float* __restrict__ gcnt,
    unsigned int* __restrict__ gticket, float* __restrict__ out)
{
    const int a = blockIdx.x;
    const int t = threadIdx.x;
    const int w = t >> 6;     // wave id 0..3
    const int l = t & 63;     // lane id
    const int s = t & 7;      // sub-lane within 8-lane row group
    const int g = t >> 3;     // row-group id 0..31

    __shared__ float  sdist[NB];   // dist[a][:]
    __shared__ int    slabel[NB];
    __shared__ int    spos[NB];    // positive indices
    __shared__ int    scount;
    __shared__ float  swred[NWV];
    __shared__ float  snegmin;

    if (t == 0) scount = 0;
    slabel[t] = labels[t];
    if (t < NB - NT) slabel[NT + t] = labels[NT + t];

    // anchor fragment: broadcast global loads (no LDS round-trip, no barrier)
    float4 u[8];
    #pragma unroll
    for (int j = 0; j < 8; ++j) u[j] = E4[a * ND4 + s + (j << 3)];

    // ---- phase 1: 12 iters x 32 rows; unroll 4 -> up to 32 loads in flight ----
    #pragma unroll 4
    for (int it = 0; it < 12; ++it) {
        const int row = (it << 5) + g;
        const float4* __restrict__ p = E4 + row * ND4 + s;
        float d = 0.f;
        #pragma unroll
        for (int j = 0; j < 8; ++j) {
            float4 v = p[j << 3];                      // 8 lanes cover 128B of row
            float dx = v.x - u[j].x, dy = v.y - u[j].y;
            float dz = v.z - u[j].z, dq = v.w - u[j].w;
            d += dx*dx + dy*dy + dz*dz + dq*dq;
        }
        d += __shfl_xor(d, 1, 64);                     // reduce within 8-lane group
        d += __shfl_xor(d, 2, 64);
        d += __shfl_xor(d, 4, 64);
        if (s == 0) sdist[row] = d;
    }
    __syncthreads();

    const int la = slabel[a];

    // ---- phase 2: negmin over row + collect positives (cols t and t+256) ----
    {
        float nm = (slabel[t] != la) ? sdist[t] : INFINITY;
        if (t < NB - NT) {
            const int c = NT + t;
            const float v = (slabel[c] != la) ? sdist[c] : INFINITY;
            nm = fminf(nm, v);
        }
        #pragma unroll
        for (int off = 32; off > 0; off >>= 1)
            nm = fminf(nm, __shfl_xor(nm, off, 64));
        if (l == 0) swred[w] = nm;
    }
    if (slabel[t] == la && t != a) {
        int idx = atomicAdd(&scount, 1);
        spos[idx] = t;
    }
    if (t < NB - NT) {
        const int c = NT + t;
        if (slabel[c] == la && c != a) {
            int idx = atomicAdd(&scount, 1);
            spos[idx] = c;
        }
    }
    __syncthreads();
    if (t == 0) {
        float m = swred[0];
        #pragma unroll
        for (int i = 1; i < NWV; ++i) m = fminf(m, swred[i]);
        snegmin = m;
    }
    __syncthreads();

    const float negmin  = snegmin;
    const int   P       = scount;
    const bool  has_neg = (negmin < INFINITY);

    // ---- phase 3: semi-hard mining, one positive per wave ----
    float lsum = 0.f;
    if (has_neg) {
        for (int pi = w; pi < P; pi += NWV) {
            const int   p  = spos[pi];
            const float dp = sdist[p];
            const float hi = dp + TMARGIN;
            float m = INFINITY;
            #pragma unroll
            for (int i = 0; i < NB / 64; ++i) {
                const int   n  = (i << 6) + l;
                const float dn = sdist[n];
                if ((slabel[n] != la) && (dn > dp) && (dn < hi))
                    m = fminf(m, dn);
            }
            #pragma unroll
            for (int off = 32; off > 0; off >>= 1)
                m = fminf(m, __shfl_xor(m, off, 64));
            if (l == 0) {
                const float dan = (m < INFINITY) ? m : negmin;
                lsum += fmaxf(dp - dan + TMARGIN, 0.f);
            }
        }
    }

    // ---- block reduce + global atomic accumulate + last-block finalize ----
    __syncthreads();               // protect swred reuse
    if (l == 0) swred[w] = lsum;
    __syncthreads();
    if (t == 0) {
        float ssum = swred[0];
        #pragma unroll
        for (int i = 1; i < NWV; ++i) ssum += swred[i];
        const float scnt = has_neg ? (float)P : 0.f;
        atomicAdd(gsum, ssum);
        atomicAdd(gcnt, scnt);
        __threadfence();                               // device-scope visibility
        const unsigned int tk = atomicAdd(gticket, 1u);
        if (tk == NB - 1) {                            // last block to arrive
            const float S = atomicAdd(gsum, 0.f);      // coherent read of total
            const float C = atomicAdd(gcnt, 0.f);
            out[0] = S / fmaxf(C, 1.f);
        }
    }
}

extern "C" void kernel_launch(void* const* d_in, const int* in_sizes, int n_in,
                              void* d_out, int out_size, void* d_ws, size_t ws_size,
                              hipStream_t stream) {
    const float4* emb  = (const float4*)d_in[0];   // (384, 256) fp32
    const int* labels  = (const int*)d_in[1];      // (384,) int32
    float* out = (float*)d_out;

    float* gsum = (float*)d_ws;                    // ws[0]
    float* gcnt = gsum + 1;                        // ws[1]
    unsigned int* gticket = (unsigned int*)d_ws + 2;

    // zero accumulators + ticket (ws is re-poisoned to 0xAA before every call)
    hipMemsetAsync(d_ws, 0, 16, stream);
    triplet_main<<<NB, NT, 0, stream>>>(emb, labels, gsum, gcnt, gticket, out);
}

// Round 5
// 65.714 us; speedup vs baseline: 1.2309x; 1.2309x over previous
//
#include <hip/hip_runtime.h>
#include <math.h>

#define NB 384          // batch size B
#define ND4 64          // D/4 = 256/4
#define NW 6            // waves per block (384 threads)
#define TMARGIN 0.3f

// One block per anchor (384 blocks x 384 threads, 6 waves).
// Phase 1: dist row via 8-lanes-per-row coalesced float4 loads (3 shuffles/8 rows).
// Phase 2: negmin + positives list. Phase 3: semi-hard mining, 1 positive/wave.
// Per-block partial (loss_sum, valid_cnt) stored to ws; tiny 1-wave kernel reduces.
// NOTE R5: no global atomics / ticket / fence — R3/R4's same-line device atomics
// (384 blocks x 3 RMW + threadfence) were suspected critical-path serialization.
__global__ __launch_bounds__(NB) void triplet_main(
    const float4* __restrict__ E4, const int* __restrict__ labels,
    float* __restrict__ ws_loss, float* __restrict__ ws_cnt)
{
    const int a = blockIdx.x;
    const int t = threadIdx.x;
    const int w = t >> 6;     // wave id 0..5
    const int l = t & 63;     // lane id
    const int s = l & 7;      // sub-lane within 8-lane row group
    const int g = l >> 3;     // row group 0..7

    __shared__ float4 sa4[ND4];    // anchor embedding (1 KB)
    __shared__ float  sdist[NB];   // dist[a][:]
    __shared__ int    slabel[NB];
    __shared__ int    spos[NB];    // positive indices
    __shared__ int    scount;
    __shared__ float  swred[NW];
    __shared__ float  snegmin;

    if (t == 0) scount = 0;
    if (t < ND4) sa4[t] = E4[a * ND4 + t];
    slabel[t] = labels[t];
    __syncthreads();

    // anchor float4s this sub-lane needs: sa4[s + 8j] (LDS broadcast reads)
    float4 u[8];
    #pragma unroll
    for (int j = 0; j < 8; ++j) u[j] = sa4[s + (j << 3)];

    // ---- phase 1: wave w computes rows [64w, 64w+64), 8 rows per iter ----
    #pragma unroll
    for (int i = 0; i < 8; ++i) {
        const int row = (w << 6) + (i << 3) + g;
        const float4* __restrict__ p = E4 + row * ND4 + s;
        float d = 0.f;
        #pragma unroll
        for (int j = 0; j < 8; ++j) {
            float4 v = p[j << 3];                      // lanes 0-7 cover 128B of row
            float dx = v.x - u[j].x, dy = v.y - u[j].y;
            float dz = v.z - u[j].z, dq = v.w - u[j].w;
            d += dx*dx + dy*dy + dz*dz + dq*dq;
        }
        d += __shfl_xor(d, 1, 64);                     // reduce within 8-lane group
        d += __shfl_xor(d, 2, 64);
        d += __shfl_xor(d, 4, 64);
        if (s == 0) sdist[row] = d;
    }
    __syncthreads();

    const int la = slabel[a];

    // ---- phase 2: negmin over row + collect positives ----
    float nm = (slabel[t] != la) ? sdist[t] : INFINITY;
    #pragma unroll
    for (int off = 32; off > 0; off >>= 1)
        nm = fminf(nm, __shfl_xor(nm, off, 64));
    if (l == 0) swred[w] = nm;
    if (slabel[t] == la && t != a) {
        int idx = atomicAdd(&scount, 1);
        spos[idx] = t;
    }
    __syncthreads();
    if (t == 0) {
        float m = swred[0];
        #pragma unroll
        for (int i = 1; i < NW; ++i) m = fminf(m, swred[i]);
        snegmin = m;
    }
    __syncthreads();

    const float negmin  = snegmin;
    const int   P       = scount;
    const bool  has_neg = (negmin < INFINITY);

    // ---- phase 3: semi-hard mining, one positive per wave ----
    float lsum = 0.f;
    if (has_neg) {
        for (int pi = w; pi < P; pi += NW) {
            const int   p  = spos[pi];
            const float dp = sdist[p];
            const float hi = dp + TMARGIN;
            float m = INFINITY;
            #pragma unroll
            for (int i = 0; i < NB / 64; ++i) {
                const int   n  = (i << 6) + l;
                const float dn = sdist[n];
                if ((slabel[n] != la) && (dn > dp) && (dn < hi))
                    m = fminf(m, dn);
            }
            #pragma unroll
            for (int off = 32; off > 0; off >>= 1)
                m = fminf(m, __shfl_xor(m, off, 64));
            if (l == 0) {
                const float dan = (m < INFINITY) ? m : negmin;
                lsum += fmaxf(dp - dan + TMARGIN, 0.f);
            }
        }
    }

    // ---- block reduce; plain per-block stores (no atomics) ----
    __syncthreads();               // protect swred reuse
    if (l == 0) swred[w] = lsum;
    __syncthreads();
    if (t == 0) {
        float ssum = swred[0];
        #pragma unroll
        for (int i = 1; i < NW; ++i) ssum += swred[i];
        ws_loss[a] = ssum;
        ws_cnt[a]  = has_neg ? (float)P : 0.f;
    }
}

// Single-wave finalize: 64 lanes x 6 strided elements, shuffle reduce, 1 store.
__global__ __launch_bounds__(64) void triplet_final(
    const float* __restrict__ ws_loss, const float* __restrict__ ws_cnt,
    float* __restrict__ out)
{
    const int l = threadIdx.x;
    float s = 0.f, c = 0.f;
    #pragma unroll
    for (int i = 0; i < NB / 64; ++i) {
        s += ws_loss[(i << 6) + l];
        c += ws_cnt [(i << 6) + l];
    }
    #pragma unroll
    for (int off = 32; off > 0; off >>= 1) {
        s += __shfl_xor(s, off, 64);
        c += __shfl_xor(c, off, 64);
    }
    if (l == 0) out[0] = s / fmaxf(c, 1.f);
}

extern "C" void kernel_launch(void* const* d_in, const int* in_sizes, int n_in,
                              void* d_out, int out_size, void* d_ws, size_t ws_size,
                              hipStream_t stream) {
    const float4* emb  = (const float4*)d_in[0];   // (384, 256) fp32
    const int* labels  = (const int*)d_in[1];      // (384,) int32
    float* out = (float*)d_out;

    float* ws_loss = (float*)d_ws;
    float* ws_cnt  = ws_loss + NB;

    triplet_main<<<NB, NB, 0, stream>>>(emb, labels, ws_loss, ws_cnt);
    triplet_final<<<1, 64, 0, stream>>>(ws_loss, ws_cnt, out);
}